// Round 5
// baseline (1810.581 us; speedup 1.0000x reference)
//
#include <hip/hip_runtime.h>

// ---------------- constants ----------------
#define DH 128
#define KTOT 1408       // 11 slots of 128: 8 rel + 3 root
#define NSLOT 11
#define DOUT2 349
#define DOUT2P 384

typedef short v8s __attribute__((ext_vector_type(8)));
typedef float v4f __attribute__((ext_vector_type(4)));

__device__ __forceinline__ unsigned short f2bf(float f) {
  unsigned int u = __float_as_uint(f);
  u += 0x7fffu + ((u >> 16) & 1u);
  return (unsigned short)(u >> 16);
}
__device__ __forceinline__ unsigned int pack2(float a, float b) {
  return (unsigned int)f2bf(a) | ((unsigned int)f2bf(b) << 16);
}
__device__ __forceinline__ void gl2lds16(const unsigned short* g, unsigned short* l) {
  __builtin_amdgcn_global_load_lds((const __attribute__((address_space(1))) unsigned int*)g,
                                   (__attribute__((address_space(3))) unsigned int*)l, 16, 0, 0);
}

// ------------- int64-vs-int32 detect + normalize -------------
__global__ void k_detect(const int* __restrict__ nt_raw, int* __restrict__ flag, int half) {
  int i = blockIdx.x * 256 + threadIdx.x;
  if (i >= half) return;
  if (nt_raw[2 * i + 1] != 0) atomicOr(flag, 1);
}
__global__ void k_cvt(const int* __restrict__ in, int* __restrict__ out, int n,
                      const int* __restrict__ flag) {
  int i = blockIdx.x * 256 + threadIdx.x;
  if (i >= n) return;
  out[i] = (*flag) ? in[i] : in[2 * i];
}

// ------------- build x [N][128] bf16 from f32 x0/x1/emb2 -------------
__global__ void k_gather(const float4* __restrict__ x0, const float4* __restrict__ x1,
                         const float4* __restrict__ x2, const int* __restrict__ nt,
                         const int* __restrict__ li, ushort4* __restrict__ xout, int total) {
  int i = blockIdx.x * 256 + threadIdx.x;
  if (i >= total) return;
  int node = i >> 5, c = i & 31;
  int t = nt[node];
  int l = li[node];
  const float4* s = (t == 0) ? x0 : (t == 1) ? x1 : x2;
  float4 v = s[(size_t)l * 32 + c];
  ushort4 o;
  o.x = f2bf(v.x); o.y = f2bf(v.y); o.z = f2bf(v.z); o.w = f2bf(v.w);
  xout[i] = o;
}

// ------------- histogram over key = dst*8 + edge_type -------------
__global__ void k_count(const int* __restrict__ src_dst, const int* __restrict__ et,
                        int* __restrict__ cnt, int E) {
  int i = blockIdx.x * 256 + threadIdx.x;
  if (i >= E) return;
  atomicAdd(&cnt[src_dst[E + i] * 8 + et[i]], 1);
}

// ------------- 3-phase exclusive scan -------------
__global__ __launch_bounds__(1024) void k_scan1(const int* __restrict__ cnt,
                                                int* __restrict__ outl,
                                                int* __restrict__ bsums, int n) {
  __shared__ int s[1024];
  int tid = threadIdx.x;
  int gid = blockIdx.x * 1024 + tid;
  int v = (gid < n) ? cnt[gid] : 0;
  s[tid] = v;
  __syncthreads();
  for (int o = 1; o < 1024; o <<= 1) {
    int t = (tid >= o) ? s[tid - o] : 0;
    __syncthreads();
    s[tid] += t;
    __syncthreads();
  }
  if (gid < n) outl[gid] = s[tid] - v;
  if (tid == 1023) bsums[blockIdx.x] = s[1023];
}
__global__ __launch_bounds__(1024) void k_scan2(int* __restrict__ bsums, int nb) {
  __shared__ int s[1024];
  int tid = threadIdx.x;
  int v = (tid < nb) ? bsums[tid] : 0;
  s[tid] = v;
  __syncthreads();
  for (int o = 1; o < 1024; o <<= 1) {
    int t = (tid >= o) ? s[tid - o] : 0;
    __syncthreads();
    s[tid] += t;
    __syncthreads();
  }
  if (tid < nb) bsums[tid] = s[tid] - v;
}
__global__ __launch_bounds__(1024) void k_scan3(int* __restrict__ offs,
                                                const int* __restrict__ bsums, int n, int total) {
  int gid = blockIdx.x * 1024 + threadIdx.x;
  if (gid < n) offs[gid] += bsums[blockIdx.x];
  if (gid == 0) offs[n] = total;
}

// ------------- scatter edge srcs into (dst,type)-sorted order -------------
__global__ void k_scatter(const int* __restrict__ src_dst, const int* __restrict__ et,
                          int* __restrict__ cur, int* __restrict__ srcs, int E) {
  int i = blockIdx.x * 256 + threadIdx.x;
  if (i >= E) return;
  int pos = atomicAdd(&cur[src_dst[E + i] * 8 + et[i]], 1);
  srcs[pos] = src_dst[i];
}

// ------------- weight prep: Wt[n][k] = bf16(concat(rel_W, root_W)[k][n]), zero-pad ----
__global__ void k_prepw(const float* __restrict__ rel,
                        const float* __restrict__ root,
                        unsigned short* __restrict__ Wt, int dout, int doutp) {
  int i = blockIdx.x * 256 + threadIdx.x;
  int tot = doutp * KTOT;
  if (i >= tot) return;
  int n = i / KTOT;
  int k = i - n * KTOT;
  unsigned short v = 0;
  if (n < dout)
    v = f2bf((k < 1024) ? rel[(size_t)k * dout + n] : root[(size_t)(k - 1024) * dout + n]);
  Wt[i] = v;
}

// ------------- FUSED aggregate+GEMM layer -------------
// Block: 128 dst nodes x (NT*128) out cols, 512 threads = 8 waves (2m x 4n grid,
// wave tile 64m x NT*32n). K-loop over 11 slots of 128; A-slot built on the fly
// (mean over (dst,rel) edges; self slots) into Al[4kk][128][32] (gather, ds_write);
// B staged per-kk via global_load_lds into Bl[NT*128][32]. Y never materialized.
template <int NT>
__global__ __launch_bounds__(512) void k_fused(const unsigned int* __restrict__ Xu,  // [N][64] bf16-pairs
                                               const unsigned short* __restrict__ Wt, // [NT*128][KTOT]
                                               const int* __restrict__ offs,
                                               const int* __restrict__ srcs,
                                               const int* __restrict__ node_type,
                                               const float* __restrict__ bias,  // [3][dout]
                                               unsigned short* __restrict__ outH,
                                               float* __restrict__ outF,
                                               int M, int dout, int relu) {
  __shared__ unsigned short Al[4 * 128 * 32];       // 32 KB
  __shared__ unsigned short Bl[NT * 128 * 32];      // 8/24 KB
  unsigned int* Alu = (unsigned int*)Al;

  const int tid = threadIdx.x;
  const int lane = tid & 63;
  const int w = tid >> 6;          // 0..7
  const int l15 = lane & 15, q = lane >> 4;
  const int wm = (w >> 2) * 64;            // m-half
  const int TN = NT * 32;
  const int wn = (w & 3) * TN;             // n-strip
  const int m0 = blockIdx.x * 128;

  v4f acc[4][2 * NT];
#pragma unroll
  for (int i = 0; i < 4; ++i)
#pragma unroll
    for (int j = 0; j < 2 * NT; ++j) acc[i][j] = (v4f){0.f, 0.f, 0.f, 0.f};

  // B staging coords (per call: 16 rows x 32 shorts = 1 KB)
  const int brow = lane >> 2, bseg = lane & 3;

#pragma unroll 1
  for (int r = 0; r < NSLOT; ++r) {
    // ---- build A-slot: 8 waves x 16 nodes; lane covers dim-pair {2*lane, 2*lane+1}
#pragma unroll 1
    for (int t = 0; t < 16; ++t) {
      int nd = w * 16 + t;
      int gn = m0 + nd;
      unsigned int val = 0u;
      if (gn < M) {
        if (r < 8) {
          int s = offs[gn * 8 + r], e = offs[gn * 8 + r + 1];
          float a0 = 0.f, a1 = 0.f, b0 = 0.f, b1 = 0.f;
          int j = s;
          for (; j + 2 <= e; j += 2) {
            int s1 = srcs[j], s2 = srcs[j + 1];
            unsigned int u1 = Xu[(size_t)s1 * 64 + lane];
            unsigned int u2 = Xu[(size_t)s2 * 64 + lane];
            a0 += __uint_as_float(u1 << 16);
            a1 += __uint_as_float(u1 & 0xffff0000u);
            b0 += __uint_as_float(u2 << 16);
            b1 += __uint_as_float(u2 & 0xffff0000u);
          }
          if (j < e) {
            unsigned int u1 = Xu[(size_t)srcs[j] * 64 + lane];
            a0 += __uint_as_float(u1 << 16);
            a1 += __uint_as_float(u1 & 0xffff0000u);
          }
          int c = e - s;
          if (c > 0) {
            float sc = 1.0f / (float)c;
            val = pack2((a0 + b0) * sc, (a1 + b1) * sc);
          }
        } else {
          val = (node_type[gn] == r - 8) ? Xu[(size_t)gn * 64 + lane] : 0u;
        }
      }
      Alu[q * 2048 + nd * 16 + l15] = val;   // Al[kk=q][nd][l15*2..+1]
    }

    // ---- per-kk: stage B slice, sync, MFMA, sync
#pragma unroll 1
    for (int kk = 0; kk < 4; ++kk) {
      // stage Bl[NT*128][32] for (slot r, kk): NT*8 calls of 16 rows
      for (int c = w; c < NT * 8; c += 8) {
        int R = c * 16;
        gl2lds16(Wt + (size_t)(R + brow) * KTOT + r * 128 + kk * 32 + bseg * 8,
                 Bl + R * 32);
      }
      __syncthreads();   // drains gather (1st kk) + B staging + prior ds activity
      v8s a[4], b[2 * NT];
#pragma unroll
      for (int ti = 0; ti < 4; ++ti)
        a[ti] = *(const v8s*)(Al + kk * 4096 + (wm + ti * 16 + l15) * 32 + q * 8);
#pragma unroll
      for (int tj = 0; tj < 2 * NT; ++tj)
        b[tj] = *(const v8s*)(Bl + (wn + tj * 16 + l15) * 32 + q * 8);
#pragma unroll
      for (int ti = 0; ti < 4; ++ti)
#pragma unroll
        for (int tj = 0; tj < 2 * NT; ++tj)
          acc[ti][tj] = __builtin_amdgcn_mfma_f32_16x16x32_bf16(a[ti], b[tj], acc[ti][tj], 0, 0, 0);
      __syncthreads();   // protect Bl (and Al on last kk) before overwrite
    }
  }

  // ---- epilogue: D col = lane&15, row = (lane>>4)*4 + reg
#pragma unroll
  for (int ti = 0; ti < 4; ++ti) {
#pragma unroll
    for (int i = 0; i < 4; ++i) {
      int row = m0 + wm + ti * 16 + q * 4 + i;
      if (row >= M) continue;
      int nt = node_type[row];
      const float* brw = bias + nt * dout;
#pragma unroll
      for (int tj = 0; tj < 2 * NT; ++tj) {
        int col = wn + tj * 16 + l15;
        if (col >= dout) continue;
        float v = acc[ti][tj][i] + brw[col];
        if (relu) {
          v = v > 0.f ? v : 0.f;
          outH[(size_t)row * dout + col] = f2bf(v);
        } else {
          outF[(size_t)row * dout + col] = v;
        }
      }
    }
  }
}

// ------------- row-wise log_softmax over 349 f32 cols, in place -------------
__global__ __launch_bounds__(256) void k_softmax(float* __restrict__ X, int M) {
  int w = blockIdx.x * 4 + (threadIdx.x >> 6);
  if (w >= M) return;
  int lane = threadIdx.x & 63;
  float* row = X + (size_t)w * DOUT2;
  float v[6];
  float mx = -3.0e38f;
#pragma unroll
  for (int i = 0; i < 6; ++i) {
    int c = lane + i * 64;
    v[i] = (c < DOUT2) ? row[c] : -3.0e38f;
    mx = fmaxf(mx, v[i]);
  }
#pragma unroll
  for (int o = 32; o > 0; o >>= 1) mx = fmaxf(mx, __shfl_xor(mx, o));
  float s = 0.f;
#pragma unroll
  for (int i = 0; i < 6; ++i) {
    int c = lane + i * 64;
    if (c < DOUT2) s += __expf(v[i] - mx);
  }
#pragma unroll
  for (int o = 32; o > 0; o >>= 1) s += __shfl_xor(s, o);
  float ls = __logf(s);
#pragma unroll
  for (int i = 0; i < 6; ++i) {
    int c = lane + i * 64;
    if (c < DOUT2) row[c] = v[i] - mx - ls;
  }
}

extern "C" void kernel_launch(void* const* d_in, const int* in_sizes, int n_in,
                              void* d_out, int out_size, void* d_ws, size_t ws_size,
                              hipStream_t stream) {
  const float* x0 = (const float*)d_in[0];
  const float* x1 = (const float*)d_in[1];
  const float* emb2 = (const float*)d_in[2];
  const float* relW1 = (const float*)d_in[3];
  const float* rootW1 = (const float*)d_in[4];
  const float* rootb1 = (const float*)d_in[5];
  const float* relW2 = (const float*)d_in[6];
  const float* rootW2 = (const float*)d_in[7];
  const float* rootb2 = (const float*)d_in[8];
  const int* ei_raw = (const int*)d_in[9];
  const int* et_raw = (const int*)d_in[10];
  const int* nt_raw = (const int*)d_in[11];
  const int* li_raw = (const int*)d_in[12];

  const int E = in_sizes[10];
  const int N = in_sizes[11];
  const int NK = N * 8;

  char* p = (char*)d_ws;
  auto alloc = [&](size_t bytes) {
    char* r = p;
    p += (bytes + 255) & ~(size_t)255;
    return r;
  };
  unsigned short* xbuf = (unsigned short*)alloc((size_t)N * DH * 2);
  unsigned short* hbuf = (unsigned short*)alloc((size_t)N * DH * 2);
  unsigned short* wt1 = (unsigned short*)alloc((size_t)128 * KTOT * 2);
  unsigned short* wt2 = (unsigned short*)alloc((size_t)DOUT2P * KTOT * 2);
  int* offs = (int*)alloc((size_t)(NK + 1) * 4);
  int* cur = (int*)alloc((size_t)NK * 4);
  int* srcs = (int*)alloc((size_t)E * 4);
  int* bsums = (int*)alloc(4096);
  int* ei32 = (int*)alloc((size_t)2 * E * 4);
  int* et32 = (int*)alloc((size_t)E * 4);
  int* nt32 = (int*)alloc((size_t)N * 4);
  int* li32 = (int*)alloc((size_t)N * 4);
  int* flag = (int*)alloc(256);

  float* outF = (float*)d_out;
  const int nScanBlocks = (NK + 1023) / 1024;
  const int mtiles = (N + 127) / 128;

  // 0. normalize integer inputs to int32
  hipMemsetAsync(flag, 0, 4, stream);
  hipMemsetAsync(cur, 0, (size_t)NK * 4, stream);
  k_detect<<<(N / 2 + 255) / 256, 256, 0, stream>>>(nt_raw, flag, N / 2);
  k_cvt<<<(2 * E + 255) / 256, 256, 0, stream>>>(ei_raw, ei32, 2 * E, flag);
  k_cvt<<<(E + 255) / 256, 256, 0, stream>>>(et_raw, et32, E, flag);
  k_cvt<<<(N + 255) / 256, 256, 0, stream>>>(nt_raw, nt32, N, flag);
  k_cvt<<<(N + 255) / 256, 256, 0, stream>>>(li_raw, li32, N, flag);

  // 1. build x (bf16)
  k_gather<<<(N * 32 + 255) / 256, 256, 0, stream>>>((const float4*)x0, (const float4*)x1,
                                                     (const float4*)emb2, nt32, li32,
                                                     (ushort4*)xbuf, N * 32);
  // 2. counting sort of edges by (dst, type)
  k_count<<<(E + 255) / 256, 256, 0, stream>>>(ei32, et32, cur, E);
  k_scan1<<<nScanBlocks, 1024, 0, stream>>>(cur, offs, bsums, NK);
  k_scan2<<<1, 1024, 0, stream>>>(bsums, nScanBlocks);
  k_scan3<<<nScanBlocks, 1024, 0, stream>>>(offs, bsums, NK, E);
  hipMemcpyAsync(cur, offs, (size_t)NK * 4, hipMemcpyDeviceToDevice, stream);
  k_scatter<<<(E + 255) / 256, 256, 0, stream>>>(ei32, et32, cur, srcs, E);
  // 3. weight prep
  k_prepw<<<(128 * KTOT + 255) / 256, 256, 0, stream>>>(relW1, rootW1, wt1, 128, 128);
  k_prepw<<<(DOUT2P * KTOT + 255) / 256, 256, 0, stream>>>(relW2, rootW2, wt2, DOUT2, DOUT2P);
  // 4. fused layer 1: h = relu(conv1(x)) -> bf16 hbuf
  k_fused<1><<<mtiles, 512, 0, stream>>>((const unsigned int*)xbuf, wt1, offs, srcs, nt32,
                                         rootb1, hbuf, (float*)nullptr, N, 128, 1);
  // 5. fused layer 2: f32 logits -> d_out
  k_fused<3><<<mtiles, 512, 0, stream>>>((const unsigned int*)hbuf, wt2, offs, srcs, nt32,
                                         rootb2, (unsigned short*)nullptr, outF, N, DOUT2, 0);
  // 6. log_softmax in place
  k_softmax<<<(N + 3) / 4, 256, 0, stream>>>(outF, N);
}